// Round 6
// baseline (246.579 us; speedup 1.0000x reference)
//
#include <hip/hip_runtime.h>

// Circle (ball) projection: out = center + (x-center) * min(1, R/max(||x-center||,1e-12))
// B = 8,388,608 points, 3 fp32 coords, AoS [B,3].
//
// R5: persistent grid-stride kernel with software pipelining.
// R0/R1/R4 (direct, LDS-transposed, 2x-MLP) all plateau at ~91-99 us
// (~3.3 TB/s aggregate). Those kernels issue one burst of loads per thread
// lifetime, then drain. This version keeps waves resident (2048 blocks =
// 8 blocks/CU = 32 waves/CU) and each thread processes 4 tiles, prefetching
// tile k+1's 6 float4 loads before computing/storing tile k -> continuous
// load issue in steady state.
//
// ngroups = B/4 = 2,097,152 4-point tiles (3 float4 per operand per tile).
// stride  = 524,288 threads. Exact fit at this size; guards kept for safety.

#define RADIUS 1.0f

typedef float fvec4 __attribute__((ext_vector_type(4)));

__device__ __forceinline__ void project4(const fvec4 xr[3], const fvec4 cr[3], fvec4 o[3])
{
    float px[12], pc[12], po[12];
#pragma unroll
    for (int k = 0; k < 3; ++k) {
#pragma unroll
        for (int j = 0; j < 4; ++j) {
            px[4*k + j] = xr[k][j];
            pc[4*k + j] = cr[k][j];
        }
    }
#pragma unroll
    for (int p = 0; p < 4; ++p) {
        float dx = px[3*p + 0] - pc[3*p + 0];
        float dy = px[3*p + 1] - pc[3*p + 1];
        float dz = px[3*p + 2] - pc[3*p + 2];
        float n  = sqrtf(dx*dx + dy*dy + dz*dz);
        float scale = fminf(1.0f, RADIUS / fmaxf(n, 1e-12f));
        po[3*p + 0] = pc[3*p + 0] + dx * scale;
        po[3*p + 1] = pc[3*p + 1] + dy * scale;
        po[3*p + 2] = pc[3*p + 2] + dz * scale;
    }
#pragma unroll
    for (int k = 0; k < 3; ++k)
        o[k] = (fvec4){po[4*k+0], po[4*k+1], po[4*k+2], po[4*k+3]};
}

template <int G>
__global__ __launch_bounds__(256) void circle_proj_pipe(
    const fvec4* __restrict__ xv,
    const fvec4* __restrict__ cv,
    fvec4* __restrict__ ov,
    int ngroups, int stride_groups)
{
    int t = blockIdx.x * blockDim.x + threadIdx.x;

    fvec4 xr[3], cr[3];
    long g0 = t;
    if (g0 < ngroups) {
        long b = g0 * 3;
#pragma unroll
        for (int k = 0; k < 3; ++k) { xr[k] = xv[b + k]; cr[k] = cv[b + k]; }
    }

#pragma unroll
    for (int it = 0; it < G; ++it) {
        long g  = (long)t + (long)it * stride_groups;
        long gn = g + stride_groups;

        fvec4 xn[3], cn[3];
        bool have_next = (it + 1 < G) && (gn < ngroups);
        if (have_next) {
            long b = gn * 3;
#pragma unroll
            for (int k = 0; k < 3; ++k) { xn[k] = xv[b + k]; cn[k] = cv[b + k]; }
        }

        if (g < ngroups) {
            fvec4 o[3];
            project4(xr, cr, o);
            long b = g * 3;
#pragma unroll
            for (int k = 0; k < 3; ++k) ov[b + k] = o[k];
        }

        if (have_next) {
#pragma unroll
            for (int k = 0; k < 3; ++k) { xr[k] = xn[k]; cr[k] = cn[k]; }
        }
    }
}

extern "C" void kernel_launch(void* const* d_in, const int* in_sizes, int n_in,
                              void* d_out, int out_size, void* d_ws, size_t ws_size,
                              hipStream_t stream) {
    const float* x = (const float*)d_in[0];   // [B,3] fp32
    const float* c = (const float*)d_in[1];   // [B,3] fp32
    float* out = (float*)d_out;

    long total_floats = in_sizes[0];          // B*3 = 25,165,824
    int ngroups = (int)(total_floats / 12);   // 4-point tiles = 2,097,152
    constexpr int G = 4;
    int nthreads = (ngroups + G - 1) / G;     // 524,288
    int block = 256;
    int grid = (nthreads + block - 1) / block;  // 2048 -> 8 blocks/CU

    circle_proj_pipe<G><<<grid, block, 0, stream>>>(
        (const fvec4*)x, (const fvec4*)c, (fvec4*)out, ngroups, nthreads);
}